// Round 1
// baseline (43.698 us; speedup 1.0000x reference)
//
#include <hip/hip_runtime.h>

#define NK 50
#define D  256

__global__ __launch_bounds__(256) void ica_kernel(
    const float* __restrict__ interest,   // [bs, 50, 256]
    const float* __restrict__ cand,       // [bs, 256]
    const int*   __restrict__ counts,     // [bs]
    float*       __restrict__ out,        // [bs, 256]
    int bs)
{
    const int b = blockIdx.x;
    if (b >= bs) return;
    const int tid  = threadIdx.x;
    const int lane = tid & 63;
    const int wave = tid >> 6;

    __shared__ float s_attn[NK];
    __shared__ float s_w[NK];
    __shared__ int   s_sel[NK];
    __shared__ int   s_nsel;

    const float* irow_base = interest + (size_t)b * NK * D;

    // candidate fragment for this lane (d = lane*4 .. lane*4+3), coalesced 16B/lane
    const float4 c4 = *reinterpret_cast<const float4*>(cand + (size_t)b * D + lane * 4);

    // ---- phase 1: scores attn[k] = <interest[b,k,:], cand[b,:]> ----
    for (int k = wave; k < NK; k += 4) {
        const float4 a4 = *reinterpret_cast<const float4*>(irow_base + (size_t)k * D + lane * 4);
        float p = a4.x * c4.x + a4.y * c4.y + a4.z * c4.z + a4.w * c4.w;
        #pragma unroll
        for (int off = 32; off >= 1; off >>= 1)
            p += __shfl_xor(p, off, 64);
        if (lane == 0) s_attn[k] = p;
    }
    __syncthreads();

    // ---- phase 2: dyn_K, exact top-k selection (stable argsort semantics) ----
    if (wave == 0) {
        int cnt = counts[b];
        if (cnt < 1) cnt = 1;
        int dynK = (int)ceilf(log2f(5.0f * (float)cnt));
        if (dynK < 1)  dynK = 1;
        if (dynK > NK) dynK = NK;

        bool  sel = false;
        if (lane < NK) {
            float my = s_attn[lane];
            int rank = 0;
            #pragma unroll 1
            for (int j = 0; j < NK; ++j) {
                float vj = s_attn[j];
                // descending stable sort: rank = #strictly-greater + #equal-with-smaller-index
                rank += (vj > my) || (vj == my && j < lane);
            }
            sel = (rank < dynK);
            s_w[lane] = sel ? my : 0.0f;
        }
        unsigned long long m = __ballot(sel);
        if (sel) {
            int pos = __popcll(m & ((1ull << lane) - 1ull));
            s_sel[pos] = lane;
        }
        if (lane == 0) s_nsel = __popcll(m);
    }
    __syncthreads();

    // ---- phase 3: user[d] = sum over selected k of attn[k] * interest[b,k,d] ----
    float acc = 0.0f;
    const int n = s_nsel;
    for (int i = 0; i < n; ++i) {
        const int k = s_sel[i];
        acc += s_w[k] * irow_base[(size_t)k * D + tid];
    }
    out[(size_t)b * D + tid] = acc;
}

extern "C" void kernel_launch(void* const* d_in, const int* in_sizes, int n_in,
                              void* d_out, int out_size, void* d_ws, size_t ws_size,
                              hipStream_t stream) {
    const float* interest = (const float*)d_in[0];   // [bs,50,256]
    const float* cand     = (const float*)d_in[1];   // [bs,256]
    const int*   counts   = (const int*)d_in[2];     // [bs]
    float*       out      = (float*)d_out;           // [bs,256]

    const int bs = in_sizes[2];                      // 4096
    ica_kernel<<<bs, 256, 0, stream>>>(interest, cand, counts, out, bs);
}

// Round 2
// 38.281 us; speedup vs baseline: 1.1415x; 1.1415x over previous
//
#include <hip/hip_runtime.h>

#define NK 50
#define D  256
#define NW 8          // waves per block (512 threads)
#define RPW 7         // ceil(NK/NW) rows per wave, register-resident

__global__ __launch_bounds__(512) void ica_kernel(
    const float* __restrict__ interest,   // [bs, 50, 256]
    const float* __restrict__ cand,       // [bs, 256]
    const int*   __restrict__ counts,     // [bs]
    float*       __restrict__ out,        // [bs, 256]
    int bs)
{
    const int b    = blockIdx.x;
    const int tid  = threadIdx.x;
    const int lane = tid & 63;
    const int wave = tid >> 6;

    __shared__ float s_attn[NK];
    __shared__ float s_w[NK];
    __shared__ float s_part[NW][D];

    const float* irow = interest + (size_t)b * NK * D;

    // candidate fragment for this lane (d = lane*4 .. lane*4+3)
    const float4 c4 = *reinterpret_cast<const float4*>(cand + (size_t)b * D + lane * 4);

    // ---- phase 1a: issue ALL row loads first (ILP), keep fragments in registers ----
    float4 frag[RPW];
    #pragma unroll
    for (int i = 0; i < RPW; ++i) {
        const int k = wave + i * NW;           // wave-uniform guard
        if (k < NK)
            frag[i] = *reinterpret_cast<const float4*>(irow + (size_t)k * D + lane * 4);
    }

    // ---- phase 1b: dot + wave reduce -> s_attn[k] ----
    #pragma unroll
    for (int i = 0; i < RPW; ++i) {
        const int k = wave + i * NW;
        if (k < NK) {
            const float4 a4 = frag[i];
            float p = a4.x * c4.x + a4.y * c4.y + a4.z * c4.z + a4.w * c4.w;
            #pragma unroll
            for (int off = 32; off >= 1; off >>= 1)
                p += __shfl_xor(p, off, 64);
            if (lane == 0) s_attn[k] = p;
        }
    }
    __syncthreads();

    // ---- phase 2: dyn_K + exact top-k (stable argsort tie semantics) -> weights ----
    if (wave == 0) {
        int cnt = counts[b];
        if (cnt < 1) cnt = 1;
        int dynK = (int)ceilf(log2f(5.0f * (float)cnt));
        if (dynK < 1)  dynK = 1;
        if (dynK > NK) dynK = NK;

        if (lane < NK) {
            const float my = s_attn[lane];
            int rank = 0;
            #pragma unroll 1
            for (int j = 0; j < NK; ++j) {
                const float vj = s_attn[j];
                rank += (vj > my) || (vj == my && j < lane);
            }
            s_w[lane] = (rank < dynK) ? my : 0.0f;
        }
    }
    __syncthreads();

    // ---- phase 3: register-resident weighted sum (no global re-read) ----
    float4 acc = {0.f, 0.f, 0.f, 0.f};
    #pragma unroll
    for (int i = 0; i < RPW; ++i) {
        const int k = wave + i * NW;
        if (k < NK) {
            const float w = s_w[k];
            acc.x += w * frag[i].x;
            acc.y += w * frag[i].y;
            acc.z += w * frag[i].z;
            acc.w += w * frag[i].w;
        }
    }
    *reinterpret_cast<float4*>(&s_part[wave][lane * 4]) = acc;   // contiguous, conflict-free
    __syncthreads();

    // ---- phase 4: cross-wave reduce + coalesced store ----
    if (tid < D) {
        float r = 0.f;
        #pragma unroll
        for (int w = 0; w < NW; ++w)
            r += s_part[w][tid];                                  // stride-1, conflict-free
        out[(size_t)b * D + tid] = r;
    }
}

extern "C" void kernel_launch(void* const* d_in, const int* in_sizes, int n_in,
                              void* d_out, int out_size, void* d_ws, size_t ws_size,
                              hipStream_t stream) {
    const float* interest = (const float*)d_in[0];   // [bs,50,256]
    const float* cand     = (const float*)d_in[1];   // [bs,256]
    const int*   counts   = (const int*)d_in[2];     // [bs]
    float*       out      = (float*)d_out;           // [bs,256]

    const int bs = in_sizes[2];                      // 4096
    ica_kernel<<<bs, 512, 0, stream>>>(interest, cand, counts, out, bs);
}